// Round 15
// baseline (141.874 us; speedup 1.0000x reference)
//
#include <hip/hip_runtime.h>
#include <hip/hip_bf16.h>
#include <cstdint>
#include <cstddef>

#define D_MODEL 1024
#define NUM_HEADS 16
#define DK_DIM 64
#define BATCH 2
#define SEQ 4096
#define MROWS (BATCH*SEQ)
#define NCHUNK 128
#define CHUNK 32

// ---- proj GEMM geometry (R7-verified): 128x128 tile, 4 waves, 2-slot dbuf ----
#define BM 128
#define BN 128
#define BK 64
#define SLOT_SH ((BM+BN)*BK)          // shorts per slot (16384 = 32KB)
#define KTILES (D_MODEL/BK)           // 16
// ---- out-proj GEMM geometry (R9/R14-verified): 256x128, 8 waves, 3-slot ----
#define OBM 256
#define OBN 128
#define ONSLOT 3
#define OSLOT_SH (OBM*BK + OBN*BK)    // 24576

typedef __attribute__((ext_vector_type(4))) float f32x4;
typedef __attribute__((ext_vector_type(8))) short bf16x8;
typedef __attribute__((ext_vector_type(4))) short s16x4;
typedef __attribute__((ext_vector_type(2))) uint32_t u32x2;
typedef __attribute__((ext_vector_type(4))) uint32_t u32x4;

__device__ __forceinline__ float b2f(short s) {
  union { uint32_t u; float f; } c; c.u = ((uint32_t)(uint16_t)s) << 16; return c.f;
}
__device__ __forceinline__ short f2b(float f) {
  union { float f; uint32_t u; } c; c.f = f;
  uint32_t u = c.u;
  u += 0x7FFFu + ((u >> 16) & 1u);
  return (short)(u >> 16);
}
__device__ __forceinline__ f32x4 b4_to_f4(s16x4 s) {
  f32x4 r;
  r.x = b2f(s.x); r.y = b2f(s.y); r.z = b2f(s.z); r.w = b2f(s.w);
  return r;
}
// packed f32x2 -> bf16x2 (RNE), gfx950 (no builtin; T12 recipe)
__device__ __forceinline__ uint32_t cvtpk(float lo, float hi) {
  uint32_t r;
  asm("v_cvt_pk_bf16_f32 %0, %1, %2" : "=v"(r) : "v"(lo), "v"(hi));
  return r;
}

// ---- 4 weight tensors in one launch; dst regions contiguous ----
__global__ __launch_bounds__(256) void cvt_w4(
    const float* __restrict__ s0, const float* __restrict__ s1,
    const float* __restrict__ s2, const float* __restrict__ s3,
    short* __restrict__ dst) {
  const int y = blockIdx.y;
  const float* s = (y == 0) ? s0 : (y == 1) ? s1 : (y == 2) ? s2 : s3;
  const int i = blockIdx.x * 256 + threadIdx.x;          // < 262144
  float4 v = reinterpret_cast<const float4*>(s)[i];
  s16x4 o;
  o.x = f2b(v.x); o.y = f2b(v.y); o.z = f2b(v.z); o.w = f2b(v.w);
  reinterpret_cast<s16x4*>(dst)[(size_t)y * (D_MODEL * D_MODEL / 4) + i] = o;
}

// -------- projection GEMM: 128x128, 4 waves, 2-slot dbuf, f32-A fused cvt ------
// R7-verified pipeline: reg-staged A (1-tile ahead) + cvt_pk + swizzled ds_write;
// B via global_load_lds (linear dest + pre-swizzled source, rule #21); counted
// vmcnt(8)/vmcnt(4) (never 0 mid-loop); 1 barrier/tile; 2 blocks/CU (64KB LDS).
// Grid (M/BM, N/BN, z): XCD = rowblock%8. z selects (A, W, bias, C).
// CSUM epilogue (R14-verified formulas, re-derived for BM=128): block = 4
// chunks x 2 heads; cg = (l0>>5) + wr*2 + (mi>>1); h = (bcol>>6) + wc.
// MFMA swapped (B first): thread owns 4 consecutive C-cols -> vector stores.
__global__ __launch_bounds__(256, 2) void gemm_proj(
    const void* __restrict__ A0, const void* __restrict__ A1,
    const void* __restrict__ A2, const short* __restrict__ Wbase,
    const float* __restrict__ b0, const float* __restrict__ b1,
    const float* __restrict__ b2, short* __restrict__ Cbase, int actmask,
    float* __restrict__ ckp, float* __restrict__ cvp)
{
  extern __shared__ __align__(16) short lds[];   // 2 slots x (A 16KB + B 16KB)
  const int tid = threadIdx.x;
  const int wid = tid >> 6;
  const int lane = tid & 63;
  const int brow = blockIdx.x * BM;
  const int bcol = blockIdx.y * BN;
  const int z = blockIdx.z;
  const int wr = wid >> 1, wc = wid & 1;

  const float* A32 = (const float*)((z == 0) ? A0 : (z == 1) ? A1 : A2);
  const float* bias = (z == 0) ? b0 : (z == 1) ? b1 : b2;
  const short* Bw = Wbase + (size_t)z * D_MODEL * D_MODEL;
  const int act = (actmask >> z) & 1;

  f32x4 acc[4][4];
#pragma unroll
  for (int i = 0; i < 4; ++i)
#pragma unroll
    for (int j = 0; j < 4; ++j)
#pragma unroll
      for (int t = 0; t < 4; ++t) acc[i][j][t] = 0.f;

  const int srow = lane >> 3;    // row within a wave's 8-row staging group
  const int gql  = lane & 7;     // granule (8 bf16 elems / 16B) index in row
  const int sgel = (gql ^ srow) * 8;   // pre-swizzled global source granule

  float4 abuf[8];                // A reg prefetch (tile t+1)

  auto loadA = [&](int t) {
    const int k0 = t * BK;
#pragma unroll
    for (int i = 0; i < 4; ++i) {
      const float* src = A32 + (size_t)(brow + i * 32 + wid * 8 + srow) * D_MODEL + k0 + gql * 8;
      abuf[2 * i]     = *reinterpret_cast<const float4*>(src);
      abuf[2 * i + 1] = *reinterpret_cast<const float4*>(src + 4);
    }
  };
  auto writeA = [&](int slot) {  // cvt + swizzled ds_write: granule -> g^(row&7)
    char* sA = (char*)(lds + slot * SLOT_SH);
#pragma unroll
    for (int i = 0; i < 4; ++i) {
      u32x4 w;
      w.x = cvtpk(abuf[2 * i].x,     abuf[2 * i].y);
      w.y = cvtpk(abuf[2 * i].z,     abuf[2 * i].w);
      w.z = cvtpk(abuf[2 * i + 1].x, abuf[2 * i + 1].y);
      w.w = cvtpk(abuf[2 * i + 1].z, abuf[2 * i + 1].w);
      const int ebyte = (i * 32 + wid * 8 + srow) * 128 + ((gql ^ srow) * 16);
      *reinterpret_cast<u32x4*>(sA + ebyte) = w;
    }
  };
  auto stageB = [&](int t, int slot) {   // 4 gload_lds, linear dest + preswz src
    short* sB = lds + slot * SLOT_SH + BM * BK;
    const int k0 = t * BK;
#pragma unroll
    for (int i = 0; i < 4; ++i) {
      const int r = i * 32 + wid * 8;
      const short* g = Bw + (size_t)(bcol + r + srow) * D_MODEL + k0 + sgel;
      __builtin_amdgcn_global_load_lds((const __attribute__((address_space(1))) void*)g,
          (__attribute__((address_space(3))) void*)(sB + r * BK), 16, 0, 0);
    }
  };

  const int lane15 = lane & 15;
  const int swz = (lane & 7) << 4;       // read-side XOR (row&7 == lane&7)
  const int kq = (lane >> 4) * 16;

  auto compute = [&](int slot) {
    const char* sAb = (const char*)(lds + slot * SLOT_SH);
    const char* sBb = sAb + BM * BK * 2;
#pragma unroll
    for (int ks = 0; ks < 2; ++ks) {
      bf16x8 Af[4], Bf[4];
#pragma unroll
      for (int mi = 0; mi < 4; ++mi)
        Af[mi] = *reinterpret_cast<const bf16x8*>(
            sAb + (wr * 64 + mi * 16 + lane15) * 128 + ((ks * 64 + kq) ^ swz));
#pragma unroll
      for (int nj = 0; nj < 4; ++nj)
        Bf[nj] = *reinterpret_cast<const bf16x8*>(
            sBb + (wc * 64 + nj * 16 + lane15) * 128 + ((ks * 64 + kq) ^ swz));
#pragma unroll
      for (int mi = 0; mi < 4; ++mi)
#pragma unroll
        for (int nj = 0; nj < 4; ++nj)
          acc[mi][nj] = __builtin_amdgcn_mfma_f32_16x16x32_bf16(Bf[nj], Af[mi], acc[mi][nj], 0, 0, 0);
    }
  };

  // prologue: tile 0 staged to slot 0; A(1) loads in flight
  loadA(0);
  asm volatile("s_waitcnt vmcnt(0)" ::: "memory");
  writeA(0);
  stageB(0, 0);        // queue: [B0:4]
  loadA(1);            // queue: [B0:4, A1:8]

#pragma unroll 1
  for (int t = 0; t < KTILES; ++t) {
    const int cur = t & 1;
    asm volatile("s_waitcnt lgkmcnt(0)" ::: "memory");   // ds_writes drained
    if (t == KTILES - 1) { asm volatile("s_waitcnt vmcnt(0)" ::: "memory"); }
    else                 { asm volatile("s_waitcnt vmcnt(8)" ::: "memory"); }  // B(t) in, A(t+1) flying
    __builtin_amdgcn_s_barrier();          // tile t ready; other-slot readers done
    __builtin_amdgcn_sched_barrier(0);
    if (t + 1 < KTILES) {
      stageB(t + 1, cur ^ 1);              // B(t+1) flies over compute(t)
      asm volatile("s_waitcnt vmcnt(4)" ::: "memory");  // A(t+1) regs ready
      writeA(cur ^ 1);
      if (t + 2 < KTILES) loadA(t + 2);
    }
    compute(cur);
  }

  // epilogue: swapped layout; CSUM per chunk-half (cp = mi>>1)
  const int csub4 = (lane >> 4) * 4;
  f32x4 csum[2][4];
#pragma unroll
  for (int cp = 0; cp < 2; ++cp)
#pragma unroll
    for (int nj = 0; nj < 4; ++nj)
#pragma unroll
      for (int t = 0; t < 4; ++t) csum[cp][nj][t] = 0.f;

#pragma unroll
  for (int mi = 0; mi < 4; ++mi) {
    const int row = brow + wr * 64 + mi * 16 + lane15;
    const size_t rowbase = (size_t)z * MROWS * D_MODEL + (size_t)row * D_MODEL;
#pragma unroll
    for (int nj = 0; nj < 4; ++nj) {
      const int col0 = bcol + wc * 64 + nj * 16 + csub4;
      const float4 bv = *reinterpret_cast<const float4*>(&bias[col0]);
      float v0 = acc[mi][nj][0] + bv.x;
      float v1 = acc[mi][nj][1] + bv.y;
      float v2 = acc[mi][nj][2] + bv.z;
      float v3 = acc[mi][nj][3] + bv.w;
      if (act) {
        v0 = (v0 > 0.f) ? (v0 + 1.f) : __expf(v0);
        v1 = (v1 > 0.f) ? (v1 + 1.f) : __expf(v1);
        v2 = (v2 > 0.f) ? (v2 + 1.f) : __expf(v2);
        v3 = (v3 > 0.f) ? (v3 + 1.f) : __expf(v3);
      }
      csum[mi >> 1][nj][0] += v0;
      csum[mi >> 1][nj][1] += v1;
      csum[mi >> 1][nj][2] += v2;
      csum[mi >> 1][nj][3] += v3;
      u32x2 w;
      w.x = cvtpk(v0, v1);
      w.y = cvtpk(v2, v3);
      *reinterpret_cast<u32x2*>(&Cbase[rowbase + col0]) = w;
    }
  }
  if (z >= 1) {
    float* dst = (z == 1) ? ckp : cvp;
    const int b  = brow >> 12;              // / SEQ
    const int l0 = brow & (SEQ - 1);
    const int h  = (bcol >> 6) + wc;
    const int bh = b * NUM_HEADS + h;
#pragma unroll
    for (int cp = 0; cp < 2; ++cp) {
#pragma unroll
      for (int nj = 0; nj < 4; ++nj) {
        f32x4 s = csum[cp][nj];
#pragma unroll
        for (int m = 1; m < 16; m <<= 1) {
          s[0] += __shfl_xor(s[0], m, 64);
          s[1] += __shfl_xor(s[1], m, 64);
          s[2] += __shfl_xor(s[2], m, 64);
          s[3] += __shfl_xor(s[3], m, 64);
        }
        if (lane15 == 0) {
          const int cg = (l0 >> 5) + wr * 2 + cp;   // global chunk
          const int d0 = nj * 16 + csub4;
          *reinterpret_cast<f32x4*>(
              &dst[((size_t)(bh * NCHUNK + cg)) * DK_DIM + d0]) = s;
        }
      }
    }
  }
}

// -------- out-projection GEMM (R14-verified): 256x128, 8 waves, 3-slot, bf16-A --
__global__ __launch_bounds__(512, 2) void gemm_out(
    const short* __restrict__ A16, const short* __restrict__ Bw,
    const float* __restrict__ bias, float* __restrict__ Cout)
{
  extern __shared__ __align__(16) short lds[];
  const int tid = threadIdx.x;
  const int wid = tid >> 6;
  const int lane = tid & 63;
  const int brow = blockIdx.x * OBM;
  const int bcol = blockIdx.y * OBN;
  const int wr = wid >> 1, wc = wid & 1;

  f32x4 acc[4][4];
#pragma unroll
  for (int i = 0; i < 4; ++i)
#pragma unroll
    for (int j = 0; j < 4; ++j)
#pragma unroll
      for (int t = 0; t < 4; ++t) acc[i][j][t] = 0.f;

  const int srow = lane >> 3;
  const int gql  = lane & 7;
  const int sgel = (gql ^ srow) * 8;

  auto stageB = [&](int t) {
    short* sB = lds + (t % ONSLOT) * OSLOT_SH + OBM * BK;
    const int k0 = t * BK;
#pragma unroll
    for (int i = 0; i < 2; ++i) {
      const int r = i * 64 + wid * 8;
      const short* g = Bw + (size_t)(bcol + r + srow) * D_MODEL + k0 + sgel;
      __builtin_amdgcn_global_load_lds((const __attribute__((address_space(1))) void*)g,
          (__attribute__((address_space(3))) void*)(sB + r * BK), 16, 0, 0);
    }
  };
  auto stageA = [&](int t) {
    short* sA = lds + (t % ONSLOT) * OSLOT_SH;
    const int k0 = t * BK;
#pragma unroll
    for (int i = 0; i < 4; ++i) {
      const int r = i * 64 + wid * 8;
      const short* g = A16 + (size_t)(brow + r + srow) * D_MODEL + k0 + sgel;
      __builtin_amdgcn_global_load_lds((const __attribute__((address_space(1))) void*)g,
          (__attribute__((address_space(3))) void*)(sA + r * BK), 16, 0, 0);
    }
  };

  const int lane15 = lane & 15;
  const int swz = (lane & 7) << 4;
  const int kq = (lane >> 4) * 16;

  auto compute = [&](int t) {
    const char* sAb = (const char*)(lds + (t % ONSLOT) * OSLOT_SH);
    const char* sBb = sAb + OBM * BK * 2;
    auto rdA = [&](int mi, int ks) -> bf16x8 {
      const int row = wr * 64 + mi * 16 + lane15;
      return *reinterpret_cast<const bf16x8*>(sAb + row * 128 + ((ks * 64 + kq) ^ swz));
    };
    auto rdB = [&](int nj, int ks) -> bf16x8 {
      const int row = wc * 64 + nj * 16 + lane15;
      return *reinterpret_cast<const bf16x8*>(sBb + row * 128 + ((ks * 64 + kq) ^ swz));
    };
    bf16x8 Af[2][2], Bf[2][2][2];
#pragma unroll
    for (int m2 = 0; m2 < 2; ++m2)
#pragma unroll
      for (int ks = 0; ks < 2; ++ks) Af[m2][ks] = rdA(m2, ks);
#pragma unroll
    for (int j2 = 0; j2 < 2; ++j2)
#pragma unroll
      for (int ks = 0; ks < 2; ++ks) Bf[0][j2][ks] = rdB(j2, ks);
#pragma unroll
    for (int m2 = 0; m2 < 2; ++m2)
#pragma unroll
      for (int j2 = 0; j2 < 2; ++j2)
#pragma unroll
        for (int ks = 0; ks < 2; ++ks)
          acc[m2][j2] = __builtin_amdgcn_mfma_f32_16x16x32_bf16(Bf[0][j2][ks], Af[m2][ks], acc[m2][j2], 0, 0, 0);
#pragma unroll
    for (int j2 = 0; j2 < 2; ++j2)
#pragma unroll
      for (int ks = 0; ks < 2; ++ks) Bf[1][j2][ks] = rdB(2 + j2, ks);
#pragma unroll
    for (int m2 = 0; m2 < 2; ++m2)
#pragma unroll
      for (int j2 = 0; j2 < 2; ++j2)
#pragma unroll
        for (int ks = 0; ks < 2; ++ks)
          acc[m2][2 + j2] = __builtin_amdgcn_mfma_f32_16x16x32_bf16(Bf[1][j2][ks], Af[m2][ks], acc[m2][2 + j2], 0, 0, 0);
#pragma unroll
    for (int m2 = 0; m2 < 2; ++m2)
#pragma unroll
      for (int ks = 0; ks < 2; ++ks) Af[m2][ks] = rdA(2 + m2, ks);
#pragma unroll
    for (int m2 = 0; m2 < 2; ++m2)
#pragma unroll
      for (int j2 = 0; j2 < 2; ++j2)
#pragma unroll
        for (int ks = 0; ks < 2; ++ks)
          acc[2 + m2][2 + j2] = __builtin_amdgcn_mfma_f32_16x16x32_bf16(Bf[1][j2][ks], Af[m2][ks], acc[2 + m2][2 + j2], 0, 0, 0);
#pragma unroll
    for (int m2 = 0; m2 < 2; ++m2)
#pragma unroll
      for (int j2 = 0; j2 < 2; ++j2)
#pragma unroll
        for (int ks = 0; ks < 2; ++ks)
          acc[2 + m2][j2] = __builtin_amdgcn_mfma_f32_16x16x32_bf16(Bf[0][j2][ks], Af[m2][ks], acc[2 + m2][j2], 0, 0, 0);
  };

  stageA(0); stageB(0);
  stageA(1); stageB(1);
#pragma unroll 1
  for (int t = 0; t < KTILES; ++t) {
    if (t == KTILES - 1) { asm volatile("s_waitcnt vmcnt(0)" ::: "memory"); }
    else                 { asm volatile("s_waitcnt vmcnt(6)" ::: "memory"); }
    __builtin_amdgcn_s_barrier();
    __builtin_amdgcn_sched_barrier(0);
    if (t + 2 < KTILES) { stageA(t + 2); stageB(t + 2); }
    compute(t);
  }

  const int csub4 = (lane >> 4) * 4;
#pragma unroll
  for (int mi = 0; mi < 4; ++mi) {
    const int row = brow + wr * 64 + mi * 16 + lane15;
    const size_t rowbase = (size_t)row * D_MODEL;
#pragma unroll
    for (int nj = 0; nj < 4; ++nj) {
      const int col0 = bcol + wc * 64 + nj * 16 + csub4;
      const float4 bv = *reinterpret_cast<const float4*>(&bias[col0]);
      float4 w;
      w.x = acc[mi][nj][0] + bv.x;
      w.y = acc[mi][nj][1] + bv.y;
      w.z = acc[mi][nj][2] + bv.z;
      w.w = acc[mi][nj][3] + bv.w;
      *reinterpret_cast<float4*>(&Cout[rowbase + col0]) = w;
    }
  }
}

// ---- pass B: exclusive scan over chunks (in place) + totals, parallelized ----
__global__ __launch_bounds__(256) void chunk_scan(
    float* __restrict__ ck, float* __restrict__ cv, float* __restrict__ ksum)
{
  __shared__ float sk[4][64], sv[4][64];
  const int bh = blockIdx.x;
  const int tid = threadIdx.x;
  const int d = tid & 63;
  const int g = tid >> 6;           // 0..3; 32 chunks per group
  const int c0 = g * 32;

  float rk = 0.f, rv = 0.f;
#pragma unroll 4
  for (int c = c0; c < c0 + 32; ++c) {
    const size_t o = ((size_t)(bh * NCHUNK + c)) * DK_DIM + d;
    rk += ck[o]; rv += cv[o];
  }
  sk[g][d] = rk; sv[g][d] = rv;
  __syncthreads();
  float runk = 0.f, runv = 0.f;
  for (int gg = 0; gg < g; ++gg) { runk += sk[gg][d]; runv += sv[gg][d]; }
#pragma unroll 4
  for (int c = c0; c < c0 + 32; ++c) {
    const size_t o = ((size_t)(bh * NCHUNK + c)) * DK_DIM + d;
    const float tk = ck[o], tv = cv[o];
    ck[o] = runk; cv[o] = runv;     // exclusive prefix
    runk += tk; runv += tv;
  }
  if (g == 3) ksum[bh * DK_DIM + d] = runk;
}

// ---------------- pass C: local cumsum + context ----------------
__global__ __launch_bounds__(256) void scan_ctx(
    const short* __restrict__ qf, const short* __restrict__ kf,
    const short* __restrict__ vf,
    const float* __restrict__ ck, const float* __restrict__ cv,
    const float* __restrict__ ksum, short* __restrict__ ctx)
{
  const int gw = blockIdx.x * 4 + (threadIdx.x >> 6);
  const int lane = threadIdx.x & 63;
  const int pg = lane >> 4;
  const int dg = lane & 15;
  const int c = gw & (NCHUNK - 1);
  const int h = (gw >> 7) & (NUM_HEADS - 1);
  const int b = gw >> 11;
  const int bh = b * NUM_HEADS + h;
  const int d4 = dg * 4;

  f32x4 krun = *reinterpret_cast<const f32x4*>(
      &ck[((size_t)(bh * NCHUNK + c)) * DK_DIM + d4]);
  f32x4 vrun = *reinterpret_cast<const f32x4*>(
      &cv[((size_t)(bh * NCHUNK + c)) * DK_DIM + d4]);
  const f32x4 kst = *reinterpret_cast<const f32x4*>(&ksum[bh * DK_DIM + d4]);

  const size_t base = ((size_t)(b * SEQ + c * CHUNK) * NUM_HEADS + h) * DK_DIM + d4;

  for (int p0 = 0; p0 < CHUNK; p0 += 4) {
    const size_t qoff = base + (size_t)(p0 + pg) * D_MODEL;
    const f32x4 q4 = b4_to_f4(*reinterpret_cast<const s16x4*>(&qf[qoff]));
    f32x4 sk, sv;
#pragma unroll
    for (int i = 0; i < 4; ++i) {
      const size_t off = base + (size_t)(p0 + i) * D_MODEL;
      krun += b4_to_f4(*reinterpret_cast<const s16x4*>(&kf[off]));
      vrun += b4_to_f4(*reinterpret_cast<const s16x4*>(&vf[off]));
      if (i == pg) { sk = krun; sv = vrun; }
    }
    float s1 = q4.x * sk.x + q4.y * sk.y + q4.z * sk.z + q4.w * sk.w;
    float s2 = q4.x * kst.x + q4.y * kst.y + q4.z * kst.z + q4.w * kst.w;
#pragma unroll
    for (int m = 1; m < 16; m <<= 1) {
      s1 += __shfl_xor(s1, m, 64);
      s2 += __shfl_xor(s2, m, 64);
    }
    const float g = s1 / (s2 + 1e-6f);
    s16x4 o;
    o.x = f2b(g * sv.x); o.y = f2b(g * sv.y);
    o.z = f2b(g * sv.z); o.w = f2b(g * sv.w);
    *reinterpret_cast<s16x4*>(&ctx[qoff]) = o;
  }
}

// ---------------- launch ----------------
extern "C" void kernel_launch(void* const* d_in, const int* in_sizes, int n_in,
                              void* d_out, int out_size, void* d_ws, size_t ws_size,
                              hipStream_t stream) {
  const float* q  = (const float*)d_in[0];
  const float* k  = (const float*)d_in[1];
  const float* v  = (const float*)d_in[2];
  const float* Wq = (const float*)d_in[3];
  const float* bq = (const float*)d_in[4];
  const float* Wk = (const float*)d_in[5];
  const float* bk = (const float*)d_in[6];
  const float* Wv = (const float*)d_in[7];
  const float* bv = (const float*)d_in[8];
  const float* Wo = (const float*)d_in[9];
  const float* bo = (const float*)d_in[10];
  float* out = (float*)d_out;

  uint8_t* p = (uint8_t*)d_ws;
  auto alloc = [&](size_t bytes) { uint8_t* r = p; p += bytes; return r; };
  short* qf  = (short*)alloc((size_t)MROWS * D_MODEL * 2);   // qf,kf,vf contiguous
  short* kf  = (short*)alloc((size_t)MROWS * D_MODEL * 2);
  short* vf  = (short*)alloc((size_t)MROWS * D_MODEL * 2);
  short* ctx = (short*)alloc((size_t)MROWS * D_MODEL * 2);
  short* Wqb = (short*)alloc((size_t)D_MODEL * D_MODEL * 2);  // Wqb..Wob contiguous
  short* Wkb = (short*)alloc((size_t)D_MODEL * D_MODEL * 2);
  short* Wvb = (short*)alloc((size_t)D_MODEL * D_MODEL * 2);
  short* Wob = (short*)alloc((size_t)D_MODEL * D_MODEL * 2);
  float* ck   = (float*)alloc((size_t)BATCH * NUM_HEADS * NCHUNK * DK_DIM * 4);
  float* cv   = (float*)alloc((size_t)BATCH * NUM_HEADS * NCHUNK * DK_DIM * 4);
  float* ksum = (float*)alloc((size_t)BATCH * NUM_HEADS * DK_DIM * 4);
  (void)Wkb; (void)Wvb;

  const dim3 gproj(MROWS / BM, D_MODEL / BN, 3);    // (64, 8, 3); XCD = x%8
  const dim3 gout (MROWS / OBM, D_MODEL / OBN, 1);  // (32, 8, 1)
  const int shproj = 2 * SLOT_SH * (int)sizeof(short);       // 65536
  const int shout  = ONSLOT * OSLOT_SH * (int)sizeof(short); // 147456

  (void)hipFuncSetAttribute((const void*)gemm_proj,
      hipFuncAttributeMaxDynamicSharedMemorySize, shproj);
  (void)hipFuncSetAttribute((const void*)gemm_out,
      hipFuncAttributeMaxDynamicSharedMemorySize, shout);

  // weights -> bf16 (one launch)
  cvt_w4<<<dim3(D_MODEL * D_MODEL / 4 / 256, 4), 256, 0, stream>>>(Wq, Wk, Wv, Wo, Wqb);

  // all 3 projections in ONE launch; elu+1 on z=0 (q), z=1 (k) -> mask 0b011.
  // Fused epilogue writes per-chunk sums of kf (z=1) -> ck and vf (z=2) -> cv.
  gemm_proj<<<gproj, 256, shproj, stream>>>(q, k, v, Wqb, bq, bk, bv, qf, 0x3, ck, cv);

  // scan (chunk_sums fused into projection epilogue; chunk_scan parallelized)
  chunk_scan<<<BATCH * NUM_HEADS, 256, 0, stream>>>(ck, cv, ksum);
  scan_ctx<<<BATCH * NUM_HEADS * NCHUNK / 4, 256, 0, stream>>>(qf, kf, vf, ck, cv, ksum, ctx);

  // output projection (bf16 A, f32 out)
  gemm_out<<<gout, 512, shout, stream>>>(ctx, Wob, bo, out);
}

// Round 16
// 136.430 us; speedup vs baseline: 1.0399x; 1.0399x over previous
//
#include <hip/hip_runtime.h>
#include <hip/hip_bf16.h>
#include <cstdint>
#include <cstddef>

#define D_MODEL 1024
#define NUM_HEADS 16
#define DK_DIM 64
#define BATCH 2
#define SEQ 4096
#define MROWS (BATCH*SEQ)
#define NCHUNK 128
#define CHUNK 32

// ---- R9 GEMM geometry (empirical best): 256x128 tile, 8 waves, 3-slot LDS ----
#define BM 256
#define BN 128
#define BK 64
#define NSLOT 3
#define SLOT_SH (BM*BK + BN*BK)       // shorts per LDS slot (24576)
#define KTILES (D_MODEL/BK)           // 16

typedef __attribute__((ext_vector_type(4))) float f32x4;
typedef __attribute__((ext_vector_type(2))) float f32x2;
typedef __attribute__((ext_vector_type(8))) short bf16x8;
typedef __attribute__((ext_vector_type(4))) short s16x4;
typedef __attribute__((ext_vector_type(2))) uint32_t u32x2;
typedef __attribute__((ext_vector_type(4))) uint32_t u32x4;

__device__ __forceinline__ float b2f(short s) {
  union { uint32_t u; float f; } c; c.u = ((uint32_t)(uint16_t)s) << 16; return c.f;
}
__device__ __forceinline__ short f2b(float f) {
  union { float f; uint32_t u; } c; c.f = f;
  uint32_t u = c.u;
  u += 0x7FFFu + ((u >> 16) & 1u);
  return (short)(u >> 16);
}
__device__ __forceinline__ f32x4 b4_to_f4(s16x4 s) {
  f32x4 r;
  r.x = b2f(s.x); r.y = b2f(s.y); r.z = b2f(s.z); r.w = b2f(s.w);
  return r;
}
// packed f32x2 -> bf16x2 (RNE), gfx950 (no builtin; T12 recipe)
__device__ __forceinline__ uint32_t cvtpk(float lo, float hi) {
  uint32_t r;
  asm("v_cvt_pk_bf16_f32 %0, %1, %2" : "=v"(r) : "v"(lo), "v"(hi));
  return r;
}

// ---- 4 weight tensors in one launch; dst regions contiguous ----
__global__ __launch_bounds__(256) void cvt_w4(
    const float* __restrict__ s0, const float* __restrict__ s1,
    const float* __restrict__ s2, const float* __restrict__ s3,
    short* __restrict__ dst) {
  const int y = blockIdx.y;
  const float* s = (y == 0) ? s0 : (y == 1) ? s1 : (y == 2) ? s2 : s3;
  const int i = blockIdx.x * 256 + threadIdx.x;          // < 262144
  float4 v = reinterpret_cast<const float4*>(s)[i];
  s16x4 o;
  o.x = f2b(v.x); o.y = f2b(v.y); o.z = f2b(v.z); o.w = f2b(v.w);
  reinterpret_cast<s16x4*>(dst)[(size_t)y * (D_MODEL * D_MODEL / 4) + i] = o;
}

// ---------------- R9 GEMM (f32-A fused cvt) + fused chunk-sums ----------------
// AFP32=1: A f32, converted in-register during staging (no separate cvt pass).
// AFP32=0: A bf16 via global_load_lds. W: [N][1024] bf16.
// 512 thr = 8 waves (4M x 2N), 64x64/wave. 3-slot rotating LDS (144KB),
// counted vmcnt (never 0 mid-loop), T2 swizzle (pre-swizzled source + read
// XOR, rule #21), flat compute. Grid (M/BM, N/BN, z): XCD = rowblock%8.
// CSUM=1: epilogue reduces per-chunk sums for z=1 (-> ckp), z=2 (-> cvp).
// MFMA swapped (B first): thread owns 4 consecutive C-cols -> 16B stores.
template<int AFP32, int OUTBF16, int CSUM>
__global__ __launch_bounds__(512, 2) void gemm8(
    const void* __restrict__ A0, const void* __restrict__ A1,
    const void* __restrict__ A2, const short* __restrict__ Wbase,
    const float* __restrict__ b0, const float* __restrict__ b1,
    const float* __restrict__ b2, void* __restrict__ Cbase, int actmask,
    float* __restrict__ ckp, float* __restrict__ cvp)
{
  extern __shared__ __align__(16) short lds[];
  const int tid = threadIdx.x;
  const int wid = tid >> 6;
  const int lane = tid & 63;
  const int brow = blockIdx.x * BM;
  const int bcol = blockIdx.y * BN;
  const int z = blockIdx.z;
  const int wr = wid >> 1, wc = wid & 1;

  const void* Ap = (z == 0) ? A0 : (z == 1) ? A1 : A2;
  const float* bias = (z == 0) ? b0 : (z == 1) ? b1 : b2;
  const short* Bw = Wbase + (size_t)z * D_MODEL * D_MODEL;
  const int act = (actmask >> z) & 1;
  const float* __restrict__ A32 = (const float*)Ap;
  const short* __restrict__ A16 = (const short*)Ap;

  f32x4 acc[4][4];
#pragma unroll
  for (int i = 0; i < 4; ++i)
#pragma unroll
    for (int j = 0; j < 4; ++j)
#pragma unroll
      for (int t = 0; t < 4; ++t) acc[i][j][t] = 0.f;

  const int srow = lane >> 3;                 // row within 8-row wave chunk
  const int gql  = lane & 7;                  // logical granule (8 elems)
  const int sgel = (gql ^ srow) * 8;          // pre-swizzled source granule

  auto stageB = [&](int t) {
    short* sB = lds + (t % NSLOT) * SLOT_SH + BM * BK;
    const int k0 = t * BK;
#pragma unroll
    for (int i = 0; i < 2; ++i) {             // B: 128 rows, 2 rounds of 64
      const int r = i * 64 + wid * 8;
      const short* g = Bw + (size_t)(bcol + r + srow) * D_MODEL + k0 + sgel;
      __builtin_amdgcn_global_load_lds((const __attribute__((address_space(1))) void*)g,
          (__attribute__((address_space(3))) void*)(sB + r * BK), 16, 0, 0);
    }
  };
  auto stageA16 = [&](int t) {
    short* sA = lds + (t % NSLOT) * SLOT_SH;
    const int k0 = t * BK;
#pragma unroll
    for (int i = 0; i < 4; ++i) {             // A: 256 rows, 4 rounds of 64
      const int r = i * 64 + wid * 8;
      const short* g = A16 + (size_t)(brow + r + srow) * D_MODEL + k0 + sgel;
      __builtin_amdgcn_global_load_lds((const __attribute__((address_space(1))) void*)g,
          (__attribute__((address_space(3))) void*)(sA + r * BK), 16, 0, 0);
    }
  };
  auto loadA32 = [&](int t, float4 (&buf)[8]) {
    const int k0 = t * BK;
#pragma unroll
    for (int i = 0; i < 4; ++i) {
      const float* src = A32 + (size_t)(brow + i * 64 + wid * 8 + srow) * D_MODEL + k0 + gql * 8;
      buf[2 * i]     = *reinterpret_cast<const float4*>(src);
      buf[2 * i + 1] = *reinterpret_cast<const float4*>(src + 4);
    }
  };
  auto writeA32 = [&](int t, float4 (&buf)[8]) {
    char* sA = (char*)(lds + (t % NSLOT) * SLOT_SH);
#pragma unroll
    for (int i = 0; i < 4; ++i) {
      u32x4 w;
      w.x = cvtpk(buf[2 * i].x,     buf[2 * i].y);
      w.y = cvtpk(buf[2 * i].z,     buf[2 * i].w);
      w.z = cvtpk(buf[2 * i + 1].x, buf[2 * i + 1].y);
      w.w = cvtpk(buf[2 * i + 1].z, buf[2 * i + 1].w);
      const int ebyte = (i * 64 + wid * 8 + srow) * 128 + ((gql ^ srow) * 16);
      *reinterpret_cast<u32x4*>(sA + ebyte) = w;
    }
  };

  const int lane15 = lane & 15;
  const int swz = (lane & 7) << 4;            // read-side XOR (row&7)
  const int kq = (lane >> 4) * 16;            // byte offset of lane's k-group

  auto compute = [&](int t) {
    const char* sAb = (const char*)(lds + (t % NSLOT) * SLOT_SH);
    const char* sBb = sAb + BM * BK * 2;
    auto rdA = [&](int mi, int ks) -> bf16x8 {
      const int row = wr * 64 + mi * 16 + lane15;
      const int off = row * 128 + ((ks * 64 + kq) ^ swz);
      return *reinterpret_cast<const bf16x8*>(sAb + off);
    };
    auto rdB = [&](int nj, int ks) -> bf16x8 {
      const int row = wc * 64 + nj * 16 + lane15;
      const int off = row * 128 + ((ks * 64 + kq) ^ swz);
      return *reinterpret_cast<const bf16x8*>(sBb + off);
    };
    bf16x8 Af[2][2], Bf[2][2][2];
    // quadrant (m0, n0)
#pragma unroll
    for (int m2 = 0; m2 < 2; ++m2)
#pragma unroll
      for (int ks = 0; ks < 2; ++ks) Af[m2][ks] = rdA(m2, ks);
#pragma unroll
    for (int j2 = 0; j2 < 2; ++j2)
#pragma unroll
      for (int ks = 0; ks < 2; ++ks) Bf[0][j2][ks] = rdB(j2, ks);
#pragma unroll
    for (int m2 = 0; m2 < 2; ++m2)
#pragma unroll
      for (int j2 = 0; j2 < 2; ++j2)
#pragma unroll
        for (int ks = 0; ks < 2; ++ks)
          acc[m2][j2] = __builtin_amdgcn_mfma_f32_16x16x32_bf16(Bf[0][j2][ks], Af[m2][ks], acc[m2][j2], 0, 0, 0);
    // quadrant (m0, n1)
#pragma unroll
    for (int j2 = 0; j2 < 2; ++j2)
#pragma unroll
      for (int ks = 0; ks < 2; ++ks) Bf[1][j2][ks] = rdB(2 + j2, ks);
#pragma unroll
    for (int m2 = 0; m2 < 2; ++m2)
#pragma unroll
      for (int j2 = 0; j2 < 2; ++j2)
#pragma unroll
        for (int ks = 0; ks < 2; ++ks)
          acc[m2][2 + j2] = __builtin_amdgcn_mfma_f32_16x16x32_bf16(Bf[1][j2][ks], Af[m2][ks], acc[m2][2 + j2], 0, 0, 0);
    // quadrant (m1, n1)
#pragma unroll
    for (int m2 = 0; m2 < 2; ++m2)
#pragma unroll
      for (int ks = 0; ks < 2; ++ks) Af[m2][ks] = rdA(2 + m2, ks);
#pragma unroll
    for (int m2 = 0; m2 < 2; ++m2)
#pragma unroll
      for (int j2 = 0; j2 < 2; ++j2)
#pragma unroll
        for (int ks = 0; ks < 2; ++ks)
          acc[2 + m2][2 + j2] = __builtin_amdgcn_mfma_f32_16x16x32_bf16(Bf[1][j2][ks], Af[m2][ks], acc[2 + m2][2 + j2], 0, 0, 0);
    // quadrant (m1, n0)
#pragma unroll
    for (int m2 = 0; m2 < 2; ++m2)
#pragma unroll
      for (int j2 = 0; j2 < 2; ++j2)
#pragma unroll
        for (int ks = 0; ks < 2; ++ks)
          acc[2 + m2][j2] = __builtin_amdgcn_mfma_f32_16x16x32_bf16(Bf[0][j2][ks], Af[m2][ks], acc[2 + m2][j2], 0, 0, 0);
  };

  if constexpr (AFP32) {
    float4 buf0[8], buf1[8];
    loadA32(0, buf0);
    asm volatile("s_waitcnt vmcnt(0)" ::: "memory");
    writeA32(0, buf0);
    loadA32(1, buf1);
    stageB(0); stageB(1);

    auto body = [&](int t, float4 (&bufW)[8], float4 (&bufL)[8]) {
      if (t == KTILES - 1) { asm volatile("s_waitcnt vmcnt(0)" ::: "memory"); }
      else                 { asm volatile("s_waitcnt vmcnt(2)" ::: "memory"); }
      if (t + 1 < KTILES) writeA32(t + 1, bufW);
      if (t + 2 < KTILES) loadA32(t + 2, bufL);
      asm volatile("s_waitcnt lgkmcnt(0)" ::: "memory");
      __builtin_amdgcn_s_barrier();
      __builtin_amdgcn_sched_barrier(0);
      if (t + 2 < KTILES) stageB(t + 2);
      compute(t);
    };
#pragma unroll 1
    for (int t2 = 0; t2 < KTILES; t2 += 2) {
      body(t2,     buf1, buf0);
      body(t2 + 1, buf0, buf1);
    }
  } else {
    stageA16(0); stageB(0);
    stageA16(1); stageB(1);
#pragma unroll 1
    for (int t = 0; t < KTILES; ++t) {
      if (t == KTILES - 1) { asm volatile("s_waitcnt vmcnt(0)" ::: "memory"); }
      else                 { asm volatile("s_waitcnt vmcnt(6)" ::: "memory"); }
      __builtin_amdgcn_s_barrier();
      __builtin_amdgcn_sched_barrier(0);
      if (t + 2 < KTILES) { stageA16(t + 2); stageB(t + 2); }
      compute(t);
    }
  }

  // epilogue: swapped layout -> row(M)=lane15-based, 4 consecutive cols/store;
  // CSUM: accumulate activated values per chunk-half (cp = mi>>1).
  const int csub4 = (lane >> 4) * 4;
  f32x4 csum[2][4];
  if constexpr (CSUM) {
#pragma unroll
    for (int cp = 0; cp < 2; ++cp)
#pragma unroll
      for (int nj = 0; nj < 4; ++nj)
#pragma unroll
        for (int t = 0; t < 4; ++t) csum[cp][nj][t] = 0.f;
  }
#pragma unroll
  for (int mi = 0; mi < 4; ++mi) {
    const int row = brow + wr * 64 + mi * 16 + lane15;
    const size_t rowbase = (size_t)z * MROWS * D_MODEL + (size_t)row * D_MODEL;
#pragma unroll
    for (int nj = 0; nj < 4; ++nj) {
      const int col0 = bcol + wc * 64 + nj * 16 + csub4;
      const float4 bv = *reinterpret_cast<const float4*>(&bias[col0]);
      float v0 = acc[mi][nj][0] + bv.x;
      float v1 = acc[mi][nj][1] + bv.y;
      float v2 = acc[mi][nj][2] + bv.z;
      float v3 = acc[mi][nj][3] + bv.w;
      if (act) {
        v0 = (v0 > 0.f) ? (v0 + 1.f) : __expf(v0);
        v1 = (v1 > 0.f) ? (v1 + 1.f) : __expf(v1);
        v2 = (v2 > 0.f) ? (v2 + 1.f) : __expf(v2);
        v3 = (v3 > 0.f) ? (v3 + 1.f) : __expf(v3);
      }
      if constexpr (CSUM) {
        csum[mi >> 1][nj][0] += v0;
        csum[mi >> 1][nj][1] += v1;
        csum[mi >> 1][nj][2] += v2;
        csum[mi >> 1][nj][3] += v3;
      }
      if (OUTBF16) {
        u32x2 w;
        w.x = cvtpk(v0, v1);
        w.y = cvtpk(v2, v3);
        *reinterpret_cast<u32x2*>(&((short*)Cbase)[rowbase + col0]) = w;
      } else {
        float4 w; w.x = v0; w.y = v1; w.z = v2; w.w = v3;
        *reinterpret_cast<float4*>(&((float*)Cbase)[rowbase + col0]) = w;
      }
    }
  }
  if constexpr (CSUM) {
    if (z >= 1) {
      float* dst = (z == 1) ? ckp : cvp;
      const int b  = brow >> 12;              // / SEQ
      const int l0 = brow & (SEQ - 1);
      const int h  = (bcol >> 6) + wc;
      const int bh = b * NUM_HEADS + h;
#pragma unroll
      for (int cp = 0; cp < 2; ++cp) {
#pragma unroll
        for (int nj = 0; nj < 4; ++nj) {
          f32x4 s = csum[cp][nj];
#pragma unroll
          for (int m = 1; m < 16; m <<= 1) {
            s[0] += __shfl_xor(s[0], m, 64);
            s[1] += __shfl_xor(s[1], m, 64);
            s[2] += __shfl_xor(s[2], m, 64);
            s[3] += __shfl_xor(s[3], m, 64);
          }
          if (lane15 == 0) {
            const int cg = (l0 >> 5) + wr * 2 + cp;   // global chunk
            const int d0 = nj * 16 + csub4;
            *reinterpret_cast<f32x4*>(
                &dst[((size_t)(bh * NCHUNK + cg)) * DK_DIM + d0]) = s;
          }
        }
      }
    }
  }
}

// ---- pass B: exclusive scan over chunks (in place) + totals, PARALLELIZED ----
// 4 chunk-groups x 2 passes: group sums -> LDS -> prefix offset -> local
// exclusive scan. Dependent chain 128 -> 32+32 iterations; 4x thread count.
__global__ __launch_bounds__(256) void chunk_scan(
    float* __restrict__ ck, float* __restrict__ cv, float* __restrict__ ksum)
{
  __shared__ float sk[4][64], sv[4][64];
  const int bh = blockIdx.x;
  const int tid = threadIdx.x;
  const int d = tid & 63;
  const int g = tid >> 6;           // 0..3; 32 chunks per group
  const int c0 = g * 32;

  float rk = 0.f, rv = 0.f;
#pragma unroll 4
  for (int c = c0; c < c0 + 32; ++c) {
    const size_t o = ((size_t)(bh * NCHUNK + c)) * DK_DIM + d;
    rk += ck[o]; rv += cv[o];
  }
  sk[g][d] = rk; sv[g][d] = rv;
  __syncthreads();
  float runk = 0.f, runv = 0.f;
  for (int gg = 0; gg < g; ++gg) { runk += sk[gg][d]; runv += sv[gg][d]; }
#pragma unroll 4
  for (int c = c0; c < c0 + 32; ++c) {
    const size_t o = ((size_t)(bh * NCHUNK + c)) * DK_DIM + d;
    const float tk = ck[o], tv = cv[o];
    ck[o] = runk; cv[o] = runv;     // exclusive prefix
    runk += tk; runv += tv;
  }
  if (g == 3) ksum[bh * DK_DIM + d] = runk;   // full-sequence k sum
}

// ---------------- pass C: local cumsum + context ----------------
__global__ __launch_bounds__(256) void scan_ctx(
    const short* __restrict__ qf, const short* __restrict__ kf,
    const short* __restrict__ vf,
    const float* __restrict__ ck, const float* __restrict__ cv,
    const float* __restrict__ ksum, short* __restrict__ ctx)
{
  const int gw = blockIdx.x * 4 + (threadIdx.x >> 6);
  const int lane = threadIdx.x & 63;
  const int pg = lane >> 4;
  const int dg = lane & 15;
  const int c = gw & (NCHUNK - 1);
  const int h = (gw >> 7) & (NUM_HEADS - 1);
  const int b = gw >> 11;
  const int bh = b * NUM_HEADS + h;
  const int d4 = dg * 4;

  f32x4 krun = *reinterpret_cast<const f32x4*>(
      &ck[((size_t)(bh * NCHUNK + c)) * DK_DIM + d4]);
  f32x4 vrun = *reinterpret_cast<const f32x4*>(
      &cv[((size_t)(bh * NCHUNK + c)) * DK_DIM + d4]);
  const f32x4 kst = *reinterpret_cast<const f32x4*>(&ksum[bh * DK_DIM + d4]);

  const size_t base = ((size_t)(b * SEQ + c * CHUNK) * NUM_HEADS + h) * DK_DIM + d4;

  for (int p0 = 0; p0 < CHUNK; p0 += 4) {
    const size_t qoff = base + (size_t)(p0 + pg) * D_MODEL;
    const f32x4 q4 = b4_to_f4(*reinterpret_cast<const s16x4*>(&qf[qoff]));
    f32x4 sk, sv;
#pragma unroll
    for (int i = 0; i < 4; ++i) {
      const size_t off = base + (size_t)(p0 + i) * D_MODEL;
      krun += b4_to_f4(*reinterpret_cast<const s16x4*>(&kf[off]));
      vrun += b4_to_f4(*reinterpret_cast<const s16x4*>(&vf[off]));
      if (i == pg) { sk = krun; sv = vrun; }
    }
    float s1 = q4.x * sk.x + q4.y * sk.y + q4.z * sk.z + q4.w * sk.w;
    float s2 = q4.x * kst.x + q4.y * kst.y + q4.z * kst.z + q4.w * kst.w;
#pragma unroll
    for (int m = 1; m < 16; m <<= 1) {
      s1 += __shfl_xor(s1, m, 64);
      s2 += __shfl_xor(s2, m, 64);
    }
    const float g = s1 / (s2 + 1e-6f);
    s16x4 o;
    o.x = f2b(g * sv.x); o.y = f2b(g * sv.y);
    o.z = f2b(g * sv.z); o.w = f2b(g * sv.w);
    *reinterpret_cast<s16x4*>(&ctx[qoff]) = o;
  }
}

// ---------------- launch ----------------
extern "C" void kernel_launch(void* const* d_in, const int* in_sizes, int n_in,
                              void* d_out, int out_size, void* d_ws, size_t ws_size,
                              hipStream_t stream) {
  const float* q  = (const float*)d_in[0];
  const float* k  = (const float*)d_in[1];
  const float* v  = (const float*)d_in[2];
  const float* Wq = (const float*)d_in[3];
  const float* bq = (const float*)d_in[4];
  const float* Wk = (const float*)d_in[5];
  const float* bk = (const float*)d_in[6];
  const float* Wv = (const float*)d_in[7];
  const float* bv = (const float*)d_in[8];
  const float* Wo = (const float*)d_in[9];
  const float* bo = (const float*)d_in[10];
  float* out = (float*)d_out;

  uint8_t* p = (uint8_t*)d_ws;
  auto alloc = [&](size_t bytes) { uint8_t* r = p; p += bytes; return r; };
  short* qf  = (short*)alloc((size_t)MROWS * D_MODEL * 2);   // qf,kf,vf contiguous
  short* kf  = (short*)alloc((size_t)MROWS * D_MODEL * 2);
  short* vf  = (short*)alloc((size_t)MROWS * D_MODEL * 2);
  short* ctx = (short*)alloc((size_t)MROWS * D_MODEL * 2);
  short* Wqb = (short*)alloc((size_t)D_MODEL * D_MODEL * 2);  // Wqb..Wob contiguous
  short* Wkb = (short*)alloc((size_t)D_MODEL * D_MODEL * 2);
  short* Wvb = (short*)alloc((size_t)D_MODEL * D_MODEL * 2);
  short* Wob = (short*)alloc((size_t)D_MODEL * D_MODEL * 2);
  float* ck   = (float*)alloc((size_t)BATCH * NUM_HEADS * NCHUNK * DK_DIM * 4);
  float* cv   = (float*)alloc((size_t)BATCH * NUM_HEADS * NCHUNK * DK_DIM * 4);
  float* ksum = (float*)alloc((size_t)BATCH * NUM_HEADS * DK_DIM * 4);
  (void)Wkb; (void)Wvb;

  // R9 mapping: x = row-block (XCD = rowblock%8 -> A-slab panels co-located)
  const dim3 gproj(MROWS / BM, D_MODEL / BN, 3);   // (32, 8, 3)
  const dim3 gout (MROWS / BM, D_MODEL / BN, 1);   // (32, 8, 1)
  const int shbytes = NSLOT * SLOT_SH * (int)sizeof(short);  // 147456

  (void)hipFuncSetAttribute((const void*)gemm8<1, 1, 1>,
      hipFuncAttributeMaxDynamicSharedMemorySize, shbytes);
  (void)hipFuncSetAttribute((const void*)gemm8<0, 0, 0>,
      hipFuncAttributeMaxDynamicSharedMemorySize, shbytes);

  // weights -> bf16 (one launch)
  cvt_w4<<<dim3(D_MODEL * D_MODEL / 4 / 256, 4), 256, 0, stream>>>(Wq, Wk, Wv, Wo, Wqb);

  // all 3 projections in ONE launch; elu+1 on z=0 (q), z=1 (k) -> mask 0b011.
  // Fused epilogue writes per-chunk sums of kf (z=1) -> ck and vf (z=2) -> cv.
  gemm8<1, 1, 1><<<gproj, 512, shbytes, stream>>>(q, k, v, Wqb, bq, bk, bv, qf, 0x3, ck, cv);

  // scan (chunk_sums fused into projection epilogue; chunk_scan parallelized)
  chunk_scan<<<BATCH * NUM_HEADS, 256, 0, stream>>>(ck, cv, ksum);
  scan_ctx<<<BATCH * NUM_HEADS * NCHUNK / 4, 256, 0, stream>>>(qf, kf, vf, ck, cv, ksum, ctx);

  // output projection (bf16 A, f32 out)
  gemm8<0, 0, 0><<<gout, 512, shbytes, stream>>>(ctx, ctx, ctx, Wob, bo, bo, bo, out, 0, nullptr, nullptr);
}